// Round 10
// baseline (229.004 us; speedup 1.0000x reference)
//
#include <hip/hip_runtime.h>
#include <stdint.h>

// ScaledDotProductAttention: B=32, S=2048, D=64, fp32 in/out, temp=8.
// Swapped-operand flash attention, 32x32x16 bf16 MFMA, fp32 accum.
// Round 10: 2-way SPLIT-KV (grid 1024, 4 blocks/CU) with REDUCED register
// pressure so the 128-VGPR budget of __launch_bounds__(256,4) holds:
//  - no cross-iteration K/V register prefetch (loads issued at loop top,
//    staged after QK^T; TLP from 16 waves/CU hides HBM latency)
//  - tr_reads in 2 batches of 8 (peak 16 regs, counted lgkmcnt(8/0))
//  - no asm register pins.
// Combine pass merges the two unnormalized halves. Fallback single-pass if
// ws too small.

#define BATCH 32
#define SEQ   2048
#define DIM   64
#define QBLK_WAVE 32
#define NWAVES 4
#define QBLK  (QBLK_WAVE*NWAVES)   // 128 q-rows per block
#define KVBLK 64
#define BUFSHORTS (KVBLK*DIM)      // 4096 shorts = 8 KiB per tensor per buffer

#define OFLOATS  (BATCH*SEQ*DIM)   // 4,194,304 floats per O partial
#define TOTQ     (BATCH*SEQ)       // 65,536 rows
#define WS_FLOATS (OFLOATS + 2*TOTQ + 2*TOTQ)

typedef __attribute__((ext_vector_type(8)))  __bf16   bf16x8;
typedef __attribute__((ext_vector_type(2)))  __bf16   bf16x2;
typedef __attribute__((ext_vector_type(16))) float    f32x16;
typedef __attribute__((ext_vector_type(2)))  unsigned uint2v;
typedef __attribute__((ext_vector_type(4)))  unsigned uint4v;

// pack two f32 -> one u32 of 2xbf16 via scalar casts (compiler fuses to
// v_cvt_pk_bf16_f32; inline-asm version measured -37%, m240)
static __device__ __forceinline__ unsigned pk(float lo, float hi) {
    bf16x2 p; p[0] = (__bf16)lo; p[1] = (__bf16)hi;
    return __builtin_bit_cast(unsigned, p);
}
static __device__ __forceinline__ float exp2v(float x) {
    float r; asm("v_exp_f32 %0, %1" : "=v"(r) : "v"(x)); return r;
}
static __device__ __forceinline__ float max3(float a, float b, float c) {
    float d; asm("v_max3_f32 %0, %1, %2, %3" : "=v"(d) : "v"(a), "v"(b), "v"(c));
    return d;
}
// value held by lane^32 (both halves active)
static __device__ __forceinline__ float other_half(float v, int hi) {
    unsigned u = __builtin_bit_cast(unsigned, v);
    uint2v r = __builtin_amdgcn_permlane32_swap(u, u, false, false);
    return __builtin_bit_cast(float, hi ? r[0] : r[1]);
}

#define MFMA32(A, B, C) __builtin_amdgcn_mfma_f32_32x32x16_bf16((A), (B), (C), 0, 0, 0)
#define TRR(dst, OFFSTR) \
    asm volatile("ds_read_b64_tr_b16 %0, %1 offset:" OFFSTR : "=v"(dst) : "v"(trb))
#define WAITL(NSTR) \
    do { asm volatile("s_waitcnt lgkmcnt(" NSTR ")" ::: "memory"); \
         __builtin_amdgcn_sched_barrier(0); } while (0)
#define SUM4(a,b,c,d) (((a)+(b)) + ((c)+(d)))

static __device__ __forceinline__ bf16x8 frag_of(uint2v r0, uint2v r1) {
    uint4v w = { r0[0], r0[1], r1[0], r1[1] };
    return __builtin_bit_cast(bf16x8, w);
}

template<bool SPLIT>
__global__ __launch_bounds__(256, SPLIT ? 4 : 2)
void attn_fwd_kernel(const float* __restrict__ q,
                     const float* __restrict__ k,
                     const float* __restrict__ v,
                     float* __restrict__ out,
                     float* __restrict__ wsO,    // half-1 O partial (unnormalized)
                     float* __restrict__ wsL,    // [2][BATCH*SEQ] row sums
                     float* __restrict__ wsM)    // [2][BATCH*SEQ] row maxes
{
    constexpr int NT = SPLIT ? (SEQ / 2 / KVBLK) : (SEQ / KVBLK);

    __shared__ unsigned short Ksh[2][BUFSHORTS];  // [key][d] bf16, 16B-chunk ^= (key&7)
    __shared__ unsigned short Vsh[2][BUFSHORTS];  // same layout

    // T1: chunked XCD swizzle (nwg%8==0 both modes); contiguous batches per XCD
    const int id = blockIdx.x;
    int batch, qtile, half;
    if (SPLIT) {
        const int swz = (id & 7) * 128 + (id >> 3);   // 1024 blocks
        batch = swz >> 5;                             // 32 blocks per batch
        half  = (swz >> 4) & 1;
        qtile = swz & 15;
    } else {
        const int swz = (id & 7) * 64 + (id >> 3);    // 512 blocks
        batch = swz >> 4;
        half  = 0;
        qtile = swz & 15;
    }

    const int t    = threadIdx.x;
    const int lane = t & 63;
    const int wid  = t >> 6;
    const int hi   = lane >> 5;
    const int l31  = lane & 31;
    const int l7   = lane & 7;

    const size_t bbase = (size_t)batch * SEQ * DIM;
    const size_t kvoff = bbase + (size_t)half * (SEQ / 2) * DIM;
    const int q0w = qtile * QBLK + wid * QBLK_WAVE;

    // ---- Q B-frags (B[k=d][n=q]: n=lane&31, k=hi*8+j per 16-d block), scale 1/8*log2e
    bf16x8 qf[4];
    {
        const float sc = 0.125f * 1.44269504088896341f;
        const float* qp = q + bbase + (size_t)(q0w + l31) * DIM + hi * 8;
        #pragma unroll
        for (int dblk = 0; dblk < 4; ++dblk) {
            float4 f0 = *(const float4*)(qp + dblk * 16);
            float4 f1 = *(const float4*)(qp + dblk * 16 + 4);
            uint4v w = { pk(f0.x * sc, f0.y * sc), pk(f0.z * sc, f0.w * sc),
                         pk(f1.x * sc, f1.y * sc), pk(f1.z * sc, f1.w * sc) };
            qf[dblk] = __builtin_bit_cast(bf16x8, w);
        }
    }

    // ---- staging: thread t covers key-row t>>2, d-range (t&3)*16 (coalesced)
    const int srow = t >> 2, sq = t & 3;
    const float* kg = k + kvoff + (size_t)srow * DIM + sq * 16;
    const float* vg = v + kvoff + (size_t)srow * DIM + sq * 16;
    const int ch0 = ((2 * sq)     ^ (srow & 7)) * 8;   // swizzled 16B-chunk offsets
    const int ch1 = ((2 * sq + 1) ^ (srow & 7)) * 8;

    // ---- tr_read per-lane base (buffer 0)
    const int bq = (l31 & 15) >> 2, ee = (lane >> 4) & 1, cc = lane & 3;
    const unsigned vb = (unsigned)(uintptr_t)&Vsh[0][0];
    const unsigned trbase = vb + (unsigned)((8 * hi + bq) * 128 +
                                            (((2 * ee + (cc >> 1)) ^ bq) * 16) + (cc & 1) * 8);

    f32x16 oacc0, oacc1;
    #pragma unroll
    for (int r = 0; r < 16; ++r) { oacc0[r] = 0.f; oacc1[r] = 0.f; }
    float m_run = 0.0f, l_run = 0.0f;   // defer-max: m stays 0 on the fast path

    // ---- prologue: stage tile 0 into buf0 (no cross-iteration reg carry)
    {
        float4 a0 = *(const float4*)(kg + 0),  a1 = *(const float4*)(kg + 4);
        float4 a2 = *(const float4*)(kg + 8),  a3 = *(const float4*)(kg + 12);
        float4 b0 = *(const float4*)(vg + 0),  b1 = *(const float4*)(vg + 4);
        float4 b2 = *(const float4*)(vg + 8),  b3 = *(const float4*)(vg + 12);
        uint4v kw0 = { pk(a0.x, a0.y), pk(a0.z, a0.w), pk(a1.x, a1.y), pk(a1.z, a1.w) };
        uint4v kw1 = { pk(a2.x, a2.y), pk(a2.z, a2.w), pk(a3.x, a3.y), pk(a3.z, a3.w) };
        uint4v vw0 = { pk(b0.x, b0.y), pk(b0.z, b0.w), pk(b1.x, b1.y), pk(b1.z, b1.w) };
        uint4v vw1 = { pk(b2.x, b2.y), pk(b2.z, b2.w), pk(b3.x, b3.y), pk(b3.z, b3.w) };
        *(uint4v*)&Ksh[0][srow * DIM + ch0] = kw0;
        *(uint4v*)&Ksh[0][srow * DIM + ch1] = kw1;
        *(uint4v*)&Vsh[0][srow * DIM + ch0] = vw0;
        *(uint4v*)&Vsh[0][srow * DIM + ch1] = vw1;
    }
    asm volatile("s_waitcnt lgkmcnt(0)" ::: "memory");

    #pragma unroll 2
    for (int tile = 0; tile < NT; ++tile) {
        const int cur = tile & 1;
        __builtin_amdgcn_s_barrier();          // raw: no vmcnt drain
        __builtin_amdgcn_sched_barrier(0);

        const unsigned short* krow = &Ksh[cur][l31 * DIM];
        const unsigned trb = trbase + (unsigned)(cur * (2 * BUFSHORTS));
        const bool haveNext = (tile + 1 < NT);

        // ---- issue next-tile global loads early (fly under QK^T MFMAs)
        float4 a0, a1, a2, a3, b0, b1, b2, b3;
        if (haveNext) {
            const float* kp = kg + (size_t)(tile + 1) * KVBLK * DIM;
            const float* vp = vg + (size_t)(tile + 1) * KVBLK * DIM;
            a0 = *(const float4*)(kp + 0);  a1 = *(const float4*)(kp + 4);
            a2 = *(const float4*)(kp + 8);  a3 = *(const float4*)(kp + 12);
            b0 = *(const float4*)(vp + 0);  b1 = *(const float4*)(vp + 4);
            b2 = *(const float4*)(vp + 8);  b3 = *(const float4*)(vp + 12);
        }

        // ---- S^T = K Q^T
        f32x16 s0, s1;
        #pragma unroll
        for (int r = 0; r < 16; ++r) { s0[r] = 0.f; s1[r] = 0.f; }
        __builtin_amdgcn_s_setprio(1);
        #pragma unroll
        for (int dblk = 0; dblk < 4; ++dblk) {
            int cofs = (((2 * dblk + hi) ^ l7) * 8);
            bf16x8 kf0 = *(const bf16x8*)&krow[cofs];
            bf16x8 kf1 = *(const bf16x8*)&krow[32 * DIM + cofs];
            s0 = MFMA32(kf0, qf[dblk], s0);
            s1 = MFMA32(kf1, qf[dblk], s1);
        }
        __builtin_amdgcn_s_setprio(0);

        // ---- stage next tile into other buffer (cvt waits on loads via vmcnt)
        if (haveNext) {
            unsigned short* kst = &Ksh[cur ^ 1][srow * DIM];
            unsigned short* vst = &Vsh[cur ^ 1][srow * DIM];
            uint4v kw0 = { pk(a0.x, a0.y), pk(a0.z, a0.w), pk(a1.x, a1.y), pk(a1.z, a1.w) };
            uint4v kw1 = { pk(a2.x, a2.y), pk(a2.z, a2.w), pk(a3.x, a3.y), pk(a3.z, a3.w) };
            uint4v vw0 = { pk(b0.x, b0.y), pk(b0.z, b0.w), pk(b1.x, b1.y), pk(b1.z, b1.w) };
            uint4v vw1 = { pk(b2.x, b2.y), pk(b2.z, b2.w), pk(b3.x, b3.y), pk(b3.z, b3.w) };
            *(uint4v*)&kst[ch0] = kw0;
            *(uint4v*)&kst[ch1] = kw1;
            *(uint4v*)&vst[ch0] = vw0;
            *(uint4v*)&vst[ch1] = vw1;
        }

        // ---- tr_read batch 0: k-slots 0,1 (16 regs live)
        uint2v a00, a01, a10, a11, c00, c01, c10, c11;
        TRR(a00, "0");    TRR(a01, "576");    // ks0, d 0-31
        TRR(c00, "64");   TRR(c01, "512");    // ks0, d 32-63
        TRR(a10, "2048"); TRR(a11, "2624");   // ks1, d 0-31
        TRR(c10, "2112"); TRR(c11, "2560");   // ks1, d 32-63

        // ---- softmax: v_max3 tree, defer-max check, exp (m==0 fast path), sum
        {
            float t0 = max3(s0[0],  s0[1],  s0[2]);
            float t1 = max3(s0[3],  s0[4],  s0[5]);
            float t2 = max3(s0[6],  s0[7],  s0[8]);
            float t3 = max3(s0[9],  s0[10], s0[11]);
            float t4 = max3(s0[12], s0[13], s0[14]);
            float t5 = max3(s0[15], s1[0],  s1[1]);
            float t6 = max3(s1[2],  s1[3],  s1[4]);
            float t7 = max3(s1[5],  s1[6],  s1[7]);
            float t8 = max3(s1[8],  s1[9],  s1[10]);
            float t9 = max3(s1[11], s1[12], s1[13]);
            float ta = fmaxf(s1[14], s1[15]);
            float u0 = max3(t0, t1, t2);
            float u1 = max3(t3, t4, t5);
            float u2 = max3(t6, t7, t8);
            float u3 = max3(t9, ta, u0);
            float pmax = max3(u1, u2, u3);
            pmax = fmaxf(pmax, other_half(pmax, hi));
            if (!__all(pmax - m_run <= 12.0f)) {    // T13: almost never taken
                float mn    = fmaxf(m_run, pmax);
                float alpha = exp2v(m_run - mn);
                m_run = mn;
                l_run *= alpha;
                #pragma unroll
                for (int r = 0; r < 16; ++r) { oacc0[r] *= alpha; oacc1[r] *= alpha; }
            }
        }
        if (__all(m_run == 0.0f)) {                 // fast path: no subtract
            #pragma unroll
            for (int r = 0; r < 16; ++r) s0[r] = exp2v(s0[r]);
            #pragma unroll
            for (int r = 0; r < 16; ++r) s1[r] = exp2v(s1[r]);
        } else {
            #pragma unroll
            for (int r = 0; r < 16; ++r) s0[r] = exp2v(s0[r] - m_run);
            #pragma unroll
            for (int r = 0; r < 16; ++r) s1[r] = exp2v(s1[r] - m_run);
        }
        {
            float x0 = SUM4(s0[0], s0[1], s0[2],  s0[3]);
            float x1 = SUM4(s0[4], s0[5], s0[6],  s0[7]);
            float x2 = SUM4(s0[8], s0[9], s0[10], s0[11]);
            float x3 = SUM4(s0[12], s0[13], s0[14], s0[15]);
            float y0 = SUM4(s1[0], s1[1], s1[2],  s1[3]);
            float y1 = SUM4(s1[4], s1[5], s1[6],  s1[7]);
            float y2 = SUM4(s1[8], s1[9], s1[10], s1[11]);
            float y3 = SUM4(s1[12], s1[13], s1[14], s1[15]);
            float rs = SUM4(SUM4(x0, x1, x2, x3), y0, y1, y2) + y3;
            rs += other_half(rs, hi);
            l_run += rs;
        }

        // ---- P^T B-frags via pk + permlane32_swap (T12)
        bf16x8 bfr0, bfr1, bfr2, bfr3;
        {
            uint2v x1 = __builtin_amdgcn_permlane32_swap(pk(s0[0], s0[1]),  pk(s0[4], s0[5]),  false, false);
            uint2v x2 = __builtin_amdgcn_permlane32_swap(pk(s0[2], s0[3]),  pk(s0[6], s0[7]),  false, false);
            uint4v w1 = { x1[0], x2[0], x1[1], x2[1] };
            bfr0 = __builtin_bit_cast(bf16x8, w1);
            uint2v y1 = __builtin_amdgcn_permlane32_swap(pk(s0[8], s0[9]),  pk(s0[12], s0[13]), false, false);
            uint2v y2 = __builtin_amdgcn_permlane32_swap(pk(s0[10], s0[11]), pk(s0[14], s0[15]), false, false);
            uint4v w2 = { y1[0], y2[0], y1[1], y2[1] };
            bfr1 = __builtin_bit_cast(bf16x8, w2);
            uint2v z1 = __builtin_amdgcn_permlane32_swap(pk(s1[0], s1[1]),  pk(s1[4], s1[5]),  false, false);
            uint2v z2 = __builtin_amdgcn_permlane32_swap(pk(s1[2], s1[3]),  pk(s1[6], s1[7]),  false, false);
            uint4v w3 = { z1[0], z2[0], z1[1], z2[1] };
            bfr2 = __builtin_bit_cast(bf16x8, w3);
            uint2v u1 = __builtin_amdgcn_permlane32_swap(pk(s1[8], s1[9]),  pk(s1[12], s1[13]), false, false);
            uint2v u2 = __builtin_amdgcn_permlane32_swap(pk(s1[10], s1[11]), pk(s1[14], s1[15]), false, false);
            uint4v w4 = { u1[0], u2[0], u1[1], u2[1] };
            bfr3 = __builtin_bit_cast(bf16x8, w4);
        }

        // ---- tr_read batch 1: k-slots 2,3
        uint2v a20, a21, a30, a31, c20, c21, c30, c31;
        TRR(a20, "4096"); TRR(a21, "4672");
        TRR(c20, "4160"); TRR(c21, "4608");
        TRR(a30, "6144"); TRR(a31, "6720");
        TRR(c30, "6208"); TRR(c31, "6656");

        // ---- PV with counted waits: queue = [stage writes][batch0][batch1]
        __builtin_amdgcn_s_setprio(1);
        WAITL("8");   // stage writes + batch0 complete
        oacc0 = MFMA32(frag_of(a00, a01), bfr0, oacc0);
        oacc1 = MFMA32(frag_of(c00, c01), bfr0, oacc1);
        oacc0 = MFMA32(frag_of(a10, a11), bfr1, oacc0);
        oacc1 = MFMA32(frag_of(c10, c11), bfr1, oacc1);
        WAITL("0");   // batch1 complete (also pre-barrier DS drain)
        oacc0 = MFMA32(frag_of(a20, a21), bfr2, oacc0);
        oacc1 = MFMA32(frag_of(c20, c21), bfr2, oacc1);
        oacc0 = MFMA32(frag_of(a30, a31), bfr3, oacc0);
        oacc1 = MFMA32(frag_of(c30, c31), bfr3, oacc1);
        __builtin_amdgcn_s_setprio(0);
    }

    // ---- epilogue
    const int qrow = q0w + l31;
    if (SPLIT) {
        // unnormalized partial; half0 -> out, half1 -> wsO; (l,m) -> ws
        float* opart = half ? wsO : out;
        float* op = opart + bbase + (size_t)qrow * DIM + 4 * hi;
        #pragma unroll
        for (int rq = 0; rq < 4; ++rq) {
            float4 o0 = { oacc0[4 * rq], oacc0[4 * rq + 1],
                          oacc0[4 * rq + 2], oacc0[4 * rq + 3] };
            float4 o1 = { oacc1[4 * rq], oacc1[4 * rq + 1],
                          oacc1[4 * rq + 2], oacc1[4 * rq + 3] };
            *(float4*)(op + 8 * rq)      = o0;
            *(float4*)(op + 32 + 8 * rq) = o1;
        }
        if (hi == 0) {
            const int lin = half * TOTQ + batch * SEQ + qrow;
            wsL[lin] = l_run;
            wsM[lin] = m_run;
        }
    } else {
        float invl = 1.0f / l_run;
        float* op = out + bbase + (size_t)qrow * DIM + 4 * hi;
        #pragma unroll
        for (int rq = 0; rq < 4; ++rq) {
            float4 o0 = { oacc0[4 * rq] * invl, oacc0[4 * rq + 1] * invl,
                          oacc0[4 * rq + 2] * invl, oacc0[4 * rq + 3] * invl };
            float4 o1 = { oacc1[4 * rq] * invl, oacc1[4 * rq + 1] * invl,
                          oacc1[4 * rq + 2] * invl, oacc1[4 * rq + 3] * invl };
            *(float4*)(op + 8 * rq)      = o0;
            *(float4*)(op + 32 + 8 * rq) = o1;
        }
    }
}

// combine: out = (e1*O1 + e2*O2) / (e1*l1 + e2*l2), ei = exp2(mi - max(m1,m2))
__global__ __launch_bounds__(256)
void combine_kernel(float* __restrict__ out, const float* __restrict__ O2,
                    const float* __restrict__ wsL, const float* __restrict__ wsM)
{
    constexpr int TOT4 = OFLOATS / 4;   // 1,048,576 float4s; 16 per q-row
    for (int i = blockIdx.x * blockDim.x + threadIdx.x; i < TOT4;
         i += gridDim.x * blockDim.x) {
        const int qg = i >> 4;          // b*SEQ + q
        float l1 = wsL[qg], l2 = wsL[TOTQ + qg];
        float m1 = wsM[qg], m2 = wsM[TOTQ + qg];
        float M  = fmaxf(m1, m2);
        float e1 = exp2f(m1 - M), e2 = exp2f(m2 - M);
        float inv = 1.0f / (e1 * l1 + e2 * l2);
        float4 o1 = ((const float4*)out)[i];
        float4 o2 = ((const float4*)O2)[i];
        float4 r = { (e1 * o1.x + e2 * o2.x) * inv,
                     (e1 * o1.y + e2 * o2.y) * inv,
                     (e1 * o1.z + e2 * o2.z) * inv,
                     (e1 * o1.w + e2 * o2.w) * inv };
        ((float4*)out)[i] = r;
    }
}

extern "C" void kernel_launch(void* const* d_in, const int* in_sizes, int n_in,
                              void* d_out, int out_size, void* d_ws, size_t ws_size,
                              hipStream_t stream) {
    const float* q = (const float*)d_in[0];
    const float* k = (const float*)d_in[1];
    const float* v = (const float*)d_in[2];
    float* out = (float*)d_out;
    float* wsO = (float*)d_ws;
    float* wsL = wsO + OFLOATS;
    float* wsM = wsL + 2 * TOTQ;
    const bool split = ws_size >= (size_t)WS_FLOATS * sizeof(float);
    if (split) {
        dim3 grid(2 * (SEQ / QBLK) * BATCH);   // 1024
        hipLaunchKernelGGL((attn_fwd_kernel<true>), grid, dim3(256), 0, stream,
                           q, k, v, out, wsO, wsL, wsM);
        hipLaunchKernelGGL(combine_kernel, dim3(2048), dim3(256), 0, stream,
                           out, wsO, wsL, wsM);
    } else {
        dim3 grid((SEQ / QBLK) * BATCH);       // 512
        hipLaunchKernelGGL((attn_fwd_kernel<false>), grid, dim3(256), 0, stream,
                           q, k, v, out, wsO, wsL, wsM);
    }
}